// Round 1
// baseline (1608.668 us; speedup 1.0000x reference)
//
#include <hip/hip_runtime.h>
#include <cstdint>
#include <cstddef>

// ---------------------------------------------------------------------------
// TED forward on MI355X. Round 1: full correct implementation.
//   - bf16 MFMA (16x16x32) GEMMs with fused epilogues, plain LDS staging
//   - decay einsum as triangular GEMM with in-register A-fragment (exp2)
//   - fp32 kept for: residual x, rmsnorm stats, nl (decay log-rate), epilogues
// ---------------------------------------------------------------------------

typedef __bf16 bf16_t;
typedef __bf16 bf16x2 __attribute__((ext_vector_type(2)));
typedef __bf16 bf16x4 __attribute__((ext_vector_type(4)));
typedef __bf16 bf16x8 __attribute__((ext_vector_type(8)));
typedef float  f32x4  __attribute__((ext_vector_type(4)));

#define TED_DIM   512
#define TED_HID   2048
#define TED_L     4
#define TED_VOCAB 32000
#define TED_B     2
#define TED_S     2048
#define TED_ROWS  4096   // B*S
#define LOG2E     1.44269504088896340736f

// ---------------------------------------------------------------------------
// fp32 -> bf16 convert (grid-stride over float4)
// ---------------------------------------------------------------------------
__global__ void cvt_kernel(const float* __restrict__ in, bf16_t* __restrict__ out, int n4)
{
    int i = blockIdx.x * blockDim.x + threadIdx.x;
    if (i < n4) {
        float4 v = ((const float4*)in)[i];
        bf16x4 o;
        o[0] = (bf16_t)v.x; o[1] = (bf16_t)v.y; o[2] = (bf16_t)v.z; o[3] = (bf16_t)v.w;
        ((bf16x4*)out)[i] = o;
    }
}

// ---------------------------------------------------------------------------
// embedding gather: x[r,:] = emb[tok[r],:]   (fp32, 128 threads/row)
// ---------------------------------------------------------------------------
__global__ void embed_kernel(const int* __restrict__ tok, const float* __restrict__ emb,
                             float* __restrict__ x)
{
    int r = blockIdx.x;
    int t = threadIdx.x;           // 0..127, 4 floats each
    int id = tok[r];
    float4 v = *(const float4*)&emb[(size_t)id * TED_DIM + t * 4];
    *(float4*)&x[(size_t)r * TED_DIM + t * 4] = v;
}

// ---------------------------------------------------------------------------
// rmsnorm (+ optional fused lambda projection -> nl2 = log_sigmoid(h.lam)*log2e)
// one block (256 thr) per row of 512
// ---------------------------------------------------------------------------
__global__ void rmsnorm_kernel(const float* __restrict__ x, const float* __restrict__ w,
                               const float* __restrict__ lam,
                               bf16_t* __restrict__ hout, float* __restrict__ nl2out)
{
    int row = blockIdx.x;
    int t = threadIdx.x;
    int lane = t & 63, wv = t >> 6;
    const float* xr = x + (size_t)row * TED_DIM;

    float2 v = *(const float2*)&xr[t * 2];
    float ss = v.x * v.x + v.y * v.y;
    #pragma unroll
    for (int off = 32; off; off >>= 1) ss += __shfl_down(ss, off, 64);

    __shared__ float red[4];
    __shared__ float sscale;
    if (lane == 0) red[wv] = ss;
    __syncthreads();
    if (t == 0) {
        float s = red[0] + red[1] + red[2] + red[3];
        sscale = rsqrtf(s * (1.0f / (float)TED_DIM) + 1e-6f);
    }
    __syncthreads();
    float scale = sscale;

    float2 wv2 = *(const float2*)&w[t * 2];
    float h0 = v.x * scale * wv2.x;
    float h1 = v.y * scale * wv2.y;
    bf16x2 hb; hb[0] = (bf16_t)h0; hb[1] = (bf16_t)h1;
    *(bf16x2*)&hout[(size_t)row * TED_DIM + t * 2] = hb;

    if (lam != nullptr) {
        float2 l2 = *(const float2*)&lam[t * 2];
        float p = h0 * l2.x + h1 * l2.y;
        #pragma unroll
        for (int off = 32; off; off >>= 1) p += __shfl_down(p, off, 64);
        if (lane == 0) red[wv] = p;
        __syncthreads();
        if (t == 0) {
            float z = red[0] + red[1] + red[2] + red[3];
            float nl = fminf(z, 0.0f) - log1pf(__expf(-fabsf(z)));  // log_sigmoid(z)
            nl2out[row] = nl * LOG2E;
        }
    }
}

// ---------------------------------------------------------------------------
// bf16 GEMM, B^T layout: out[m,n] = sum_k A[m,k] * B[n,k]
// A: [M,K] row-major bf16, B: [N,K] row-major bf16. BK=32, 256 threads.
// Epilogues fused via EPI template param.
// ---------------------------------------------------------------------------
enum { EPI_BF16 = 0, EPI_F32 = 1, EPI_GMUL_ADDX = 2, EPI_ADDX = 3, EPI_SILUMUL = 4 };

template <int BM, int BN, int EPI>
__global__ __launch_bounds__(256)
void gemm_bt(const bf16_t* __restrict__ A, const bf16_t* __restrict__ B,
             int M, int N, int K,
             float* __restrict__ outf, bf16_t* __restrict__ outb,
             const float* __restrict__ gmul, const bf16_t* __restrict__ umul,
             float* __restrict__ xres)
{
    constexpr int TM = BM / 32, TN = BN / 32;
    __shared__ __align__(16) bf16_t sA[BM * 32];
    __shared__ __align__(16) bf16_t sB[BN * 32];

    int t = threadIdx.x;
    int lane = t & 63, w = t >> 6;
    int quad = lane >> 4, l16 = lane & 15;
    int m0 = blockIdx.y * BM, n0 = blockIdx.x * BN;
    int wm = (w & 1) * (BM / 2), wn = (w >> 1) * (BN / 2);
    int srow = t >> 2, skc = t & 3;   // staging: row 0..63 per issue, 16B k-chunk

    f32x4 acc[TM][TN] = {};

    for (int k0 = 0; k0 < K; k0 += 32) {
        #pragma unroll
        for (int i = 0; i < BM / 64; i++) {
            int r = i * 64 + srow;
            bf16x8 v = *(const bf16x8*)&A[(size_t)(m0 + r) * K + k0 + skc * 8];
            *(bf16x8*)&sA[r * 32 + skc * 8] = v;
        }
        #pragma unroll
        for (int i = 0; i < BN / 64; i++) {
            int r = i * 64 + srow;
            bf16x8 v = *(const bf16x8*)&B[(size_t)(n0 + r) * K + k0 + skc * 8];
            *(bf16x8*)&sB[r * 32 + skc * 8] = v;
        }
        __syncthreads();
        bf16x8 af[TM], bfr[TN];
        #pragma unroll
        for (int i = 0; i < TM; i++)
            af[i] = *(const bf16x8*)&sA[(wm + i * 16 + l16) * 32 + quad * 8];
        #pragma unroll
        for (int j = 0; j < TN; j++)
            bfr[j] = *(const bf16x8*)&sB[(wn + j * 16 + l16) * 32 + quad * 8];
        #pragma unroll
        for (int i = 0; i < TM; i++)
            #pragma unroll
            for (int j = 0; j < TN; j++)
                acc[i][j] = __builtin_amdgcn_mfma_f32_16x16x32_bf16(af[i], bfr[j], acc[i][j], 0, 0, 0);
        __syncthreads();
    }

    // epilogue: C/D layout col = lane&15, row = quad*4 + r  [m89/m91 verified]
    #pragma unroll
    for (int i = 0; i < TM; i++) {
        #pragma unroll
        for (int j = 0; j < TN; j++) {
            int col = n0 + wn + j * 16 + l16;
            #pragma unroll
            for (int r = 0; r < 4; r++) {
                int rowg = m0 + wm + i * 16 + quad * 4 + r;
                size_t idx = (size_t)rowg * N + col;
                float v = acc[i][j][r];
                if constexpr (EPI == EPI_BF16) {
                    outb[idx] = (bf16_t)v;
                } else if constexpr (EPI == EPI_F32) {
                    outf[idx] = v;
                } else if constexpr (EPI == EPI_GMUL_ADDX) {
                    xres[idx] += v * gmul[idx];
                } else if constexpr (EPI == EPI_ADDX) {
                    xres[idx] += v;
                } else { // EPI_SILUMUL: t = u * silu(v)
                    float u = (float)umul[idx];
                    float s = v / (1.0f + __expf(-v));
                    outb[idx] = (bf16_t)(u * s);
                }
            }
        }
    }
}

template <int BM, int BN, int EPI>
static void launch_gemm(hipStream_t s, const bf16_t* A, const bf16_t* B,
                        int M, int N, int K,
                        float* outf = nullptr, bf16_t* outb = nullptr,
                        const float* gmul = nullptr, const bf16_t* umul = nullptr,
                        float* xres = nullptr)
{
    dim3 grid(N / BN, M / BM);
    gemm_bt<BM, BN, EPI><<<grid, 256, 0, s>>>(A, B, M, N, K, outf, outb, gmul, umul, xres);
}

// ---------------------------------------------------------------------------
// decay einsum: aout[b*S+i, d] = silu( sum_{j<=i} exp2(nl2[b*S+j]*(i-j)) * q[b,j,d] )
// q supplied transposed: qT[d, b*S+j]  ([DIM, ROWS] row-major bf16)
// block: 64 i-rows x 128 d-cols, A-fragment (decay) computed in-registers.
// ---------------------------------------------------------------------------
__global__ __launch_bounds__(256)
void decay_kernel(const bf16_t* __restrict__ qT, const float* __restrict__ nl2,
                  bf16_t* __restrict__ aout)
{
    constexpr int BI = 64, BD = 128;
    __shared__ __align__(16) bf16_t sQ[BD * 32];

    int t = threadIdx.x;
    int lane = t & 63, w = t >> 6;
    int quad = lane >> 4, l16 = lane & 15;
    int d0 = blockIdx.x * BD;
    int i0 = blockIdx.y * BI;
    int b  = blockIdx.z;
    int wm = (w & 1) * 32, wn = (w >> 1) * 64;   // TM=2, TN=4
    int srow = t >> 2, skc = t & 3;

    f32x4 acc[2][4] = {};

    int jt_end = i0 + BI;   // causal: j <= i0+63
    for (int j0 = 0; j0 < jt_end; j0 += 32) {
        #pragma unroll
        for (int i = 0; i < 2; i++) {
            int r = i * 64 + srow;
            bf16x8 v = *(const bf16x8*)&qT[(size_t)(d0 + r) * TED_ROWS + b * TED_S + j0 + skc * 8];
            *(bf16x8*)&sQ[r * 32 + skc * 8] = v;
        }
        // decay A-fragments in registers: A[m=l16][k=quad*8+jj]
        float4 nA = *(const float4*)&nl2[b * TED_S + j0 + quad * 8];
        float4 nB = *(const float4*)&nl2[b * TED_S + j0 + quad * 8 + 4];
        float nn[8] = {nA.x, nA.y, nA.z, nA.w, nB.x, nB.y, nB.z, nB.w};
        bf16x8 af[2];
        #pragma unroll
        for (int i = 0; i < 2; i++) {
            int mi = i0 + wm + i * 16 + l16;
            #pragma unroll
            for (int jj = 0; jj < 8; jj++) {
                int j = j0 + quad * 8 + jj;
                int tt = mi - j;
                float dv = (tt >= 0) ? exp2f(nn[jj] * (float)tt) : 0.0f;
                af[i][jj] = (bf16_t)dv;
            }
        }
        __syncthreads();
        bf16x8 bfr[4];
        #pragma unroll
        for (int j = 0; j < 4; j++)
            bfr[j] = *(const bf16x8*)&sQ[(wn + j * 16 + l16) * 32 + quad * 8];
        #pragma unroll
        for (int i = 0; i < 2; i++)
            #pragma unroll
            for (int j = 0; j < 4; j++)
                acc[i][j] = __builtin_amdgcn_mfma_f32_16x16x32_bf16(af[i], bfr[j], acc[i][j], 0, 0, 0);
        __syncthreads();
    }

    #pragma unroll
    for (int i = 0; i < 2; i++) {
        #pragma unroll
        for (int j = 0; j < 4; j++) {
            int d = d0 + wn + j * 16 + l16;
            #pragma unroll
            for (int r = 0; r < 4; r++) {
                int ig = i0 + wm + i * 16 + quad * 4 + r;
                float v = acc[i][j][r];
                float s = v / (1.0f + __expf(-v));   // silu fused
                aout[(size_t)(b * TED_S + ig) * TED_DIM + d] = (bf16_t)s;
            }
        }
    }
}

// ---------------------------------------------------------------------------
// host side
// ---------------------------------------------------------------------------
extern "C" void kernel_launch(void* const* d_in, const int* in_sizes, int n_in,
                              void* d_out, int out_size, void* d_ws, size_t ws_size,
                              hipStream_t stream)
{
    const int*   tokens       = (const int*)d_in[0];
    const float* emb          = (const float*)d_in[1];
    const float* decay_norm_w = (const float*)d_in[2];
    const float* lambda_w     = (const float*)d_in[3];
    const float* quantity_w   = (const float*)d_in[4];
    const float* gate_w       = (const float*)d_in[5];
    const float* output_w     = (const float*)d_in[6];
    const float* ffn_norm_w   = (const float*)d_in[7];
    const float* w_h          = (const float*)d_in[8];
    const float* w_g          = (const float*)d_in[9];
    const float* w_o          = (const float*)d_in[10];
    const float* out_norm_w   = (const float*)d_in[11];

    constexpr int D = TED_DIM, H = TED_HID, L = TED_L, V = TED_VOCAB, R = TED_ROWS;

    char* ws = (char*)d_ws;
    size_t off = 0;
    auto alloc = [&](size_t bytes) -> char* {
        char* p = ws + off;
        off += (bytes + 255) & ~(size_t)255;
        return p;
    };
    bf16_t* emb_bf = (bf16_t*)alloc((size_t)V * D * 2);
    bf16_t* qw_bf  = (bf16_t*)alloc((size_t)L * D * D * 2);
    bf16_t* gw_bf  = (bf16_t*)alloc((size_t)L * D * D * 2);
    bf16_t* ow_bf  = (bf16_t*)alloc((size_t)L * D * D * 2);
    bf16_t* wh_bf  = (bf16_t*)alloc((size_t)L * H * D * 2);
    bf16_t* wg_bf  = (bf16_t*)alloc((size_t)L * H * D * 2);
    bf16_t* wo_bf  = (bf16_t*)alloc((size_t)L * D * H * 2);
    float*  x      = (float*)alloc((size_t)R * D * 4);
    bf16_t* h_bf   = (bf16_t*)alloc((size_t)R * D * 2);
    float*  nl2    = (float*)alloc((size_t)R * 4);
    bf16_t* qT_bf  = (bf16_t*)alloc((size_t)D * R * 2);
    float*  g_f32  = (float*)alloc((size_t)R * D * 4);
    bf16_t* a_bf   = (bf16_t*)alloc((size_t)R * D * 2);
    bf16_t* f_bf   = (bf16_t*)alloc((size_t)R * D * 2);
    bf16_t* u_bf   = (bf16_t*)alloc((size_t)R * H * 2);
    bf16_t* t_bf   = (bf16_t*)alloc((size_t)R * H * 2);
    if (off > ws_size) return;   // workspace too small -> leave d_out poisoned (visible failure)

    auto cvt = [&](const float* src, bf16_t* dst, size_t n) {
        int n4 = (int)(n / 4);
        cvt_kernel<<<dim3((n4 + 255) / 256), dim3(256), 0, stream>>>(src, dst, n4);
    };
    cvt(emb,        emb_bf, (size_t)V * D);
    cvt(quantity_w, qw_bf,  (size_t)L * D * D);
    cvt(gate_w,     gw_bf,  (size_t)L * D * D);
    cvt(output_w,   ow_bf,  (size_t)L * D * D);
    cvt(w_h,        wh_bf,  (size_t)L * H * D);
    cvt(w_g,        wg_bf,  (size_t)L * H * D);
    cvt(w_o,        wo_bf,  (size_t)L * D * H);

    embed_kernel<<<dim3(R), dim3(128), 0, stream>>>(tokens, emb, x);

    for (int l = 0; l < L; l++) {
        // h = rmsnorm(x, decay_norm_w[l]); nl2 = log_sigmoid(h . lambda)*log2e
        rmsnorm_kernel<<<dim3(R), dim3(256), 0, stream>>>(
            x, decay_norm_w + (size_t)l * D, lambda_w + (size_t)l * D, h_bf, nl2);
        // g = h @ gate_w^T  (fp32, used as multiplier)
        launch_gemm<64, 64, EPI_F32>(stream, h_bf, gw_bf + (size_t)l * D * D, R, D, D, g_f32);
        // qT = quantity_w @ h^T   -> [D, R] bf16 (transposed q for decay kernel)
        launch_gemm<64, 64, EPI_BF16>(stream, qw_bf + (size_t)l * D * D, h_bf, D, R, D,
                                      nullptr, qT_bf);
        // a = silu(decay @ q)
        decay_kernel<<<dim3(D / 128, TED_S / 64, TED_B), dim3(256), 0, stream>>>(qT_bf, nl2, a_bf);
        // x += (a @ output_w^T) * g
        launch_gemm<64, 64, EPI_GMUL_ADDX>(stream, a_bf, ow_bf + (size_t)l * D * D, R, D, D,
                                           nullptr, nullptr, g_f32, nullptr, x);
        // f = rmsnorm(x, ffn_norm_w[l])
        rmsnorm_kernel<<<dim3(R), dim3(256), 0, stream>>>(
            x, ffn_norm_w + (size_t)l * D, nullptr, f_bf, nullptr);
        // u = f @ w_h^T   [R, H] bf16
        launch_gemm<128, 128, EPI_BF16>(stream, f_bf, wh_bf + (size_t)l * H * D, R, H, D,
                                        nullptr, u_bf);
        // t = u * silu(f @ w_g^T)
        launch_gemm<128, 128, EPI_SILUMUL>(stream, f_bf, wg_bf + (size_t)l * H * D, R, H, D,
                                           nullptr, t_bf, nullptr, u_bf, nullptr);
        // x += t @ w_o^T
        launch_gemm<64, 64, EPI_ADDX>(stream, t_bf, wo_bf + (size_t)l * D * H, R, D, H,
                                      nullptr, nullptr, nullptr, nullptr, x);
    }

    // logits = rmsnorm(x, out_norm_w) @ emb^T  -> d_out fp32 [R, V]
    rmsnorm_kernel<<<dim3(R), dim3(256), 0, stream>>>(x, out_norm_w, nullptr, f_bf, nullptr);
    launch_gemm<128, 128, EPI_F32>(stream, f_bf, emb_bf, R, V, D, (float*)d_out);
}